// Round 13
// baseline (54.129 us; speedup 1.0000x reference)
//
#include <hip/hip_runtime.h>

// EXL2Linear — faithful to the reference's (quirky) unpack indexing:
// only W[:, 0:64] receives quantized codes; W[:, 64:] == qzero broadcast.
// out[r,o] = s0(o) * sum_{j<64} x[r,j]*uq(o,j) + sum_g qzero[o,g]*gsum[r,g] + bias[o]
// Collapsed to a K=96 bf16 MFMA GEMM: xg[rows][96] @ weff[O][96]^T.
// Round-12 structure with REGULAR (through-L2) dwordx4 stores instead of NT:
// dirty-line eviction is a hardware background stream (fill-kernel path),
// decoupled from wave scheduling, vs NT's drain-at-HBM completion.

constexpr int IFEAT  = 4096;
constexpr int OFEAT  = 4096;
constexpr int GROUPS = 32;   // IFEAT / 128
constexpr int KD     = 96;   // 64 quantized cols + 32 group sums
constexpr int KDP    = 100;  // padded LDS row (shorts): 50-word stride -> 2-way (free)
constexpr int WBLKS  = OFEAT / 256;  // 16 weff-prep blocks
constexpr int LTP    = 68;   // epilogue scratch row pitch (floats)

using short8 = __attribute__((ext_vector_type(8))) short;
using f32x4  = __attribute__((ext_vector_type(4))) float;
using f32x16 = __attribute__((ext_vector_type(16))) float;

static __device__ __forceinline__ unsigned short f2bf(float f) {
    union { float f; unsigned int u; } v; v.f = f;
    unsigned int lsb = (v.u >> 16) & 1;
    v.u += 0x7fff + lsb;           // round-to-nearest-even
    return (unsigned short)(v.u >> 16);
}

// ---------------- Fused prep: blocks [0,WBLKS) build weff[O][96];
// blocks [WBLKS, WBLKS+rows) build xg[row][96]. 8208 blocks = full TLP,
// read-bound at ~6.4 TB/s.
__global__ __launch_bounds__(256) void prep_kernel(const float* __restrict__ x,
                                                   const int* __restrict__ qweight,
                                                   const float* __restrict__ qscale,
                                                   const int* __restrict__ qzero,
                                                   unsigned short* __restrict__ xg,
                                                   unsigned short* __restrict__ weff) {
    const int t = threadIdx.x;
    if (blockIdx.x < WBLKS) {
        // ---- weff rows (dispatched first; tiny)
        const int o = blockIdx.x * 256 + t;
        const float s0 = qscale[(size_t)o * GROUPS];  // group-0 scale
        const unsigned int* qw = (const unsigned int*)qweight + (size_t)o * (IFEAT / 8);
        unsigned int q[8];
        #pragma unroll
        for (int c = 0; c < 8; ++c) q[c] = qw[c];
        unsigned short* wr = weff + (size_t)o * KD;
        #pragma unroll
        for (int j = 0; j < 64; ++j) {
            const int c = j & 7;
            const int i = j >> 3;
            const float uq = (float)((q[c] >> (i * 4)) & 15u);
            wr[j] = f2bf(uq * s0);
        }
        #pragma unroll
        for (int g = 0; g < GROUPS; ++g) {
            wr[64 + g] = f2bf((float)qzero[(size_t)o * GROUPS + g]);
        }
        return;
    }
    // ---- xg row
    const int row = blockIdx.x - WBLKS;
    const float4* __restrict__ x4 = (const float4*)(x + (size_t)row * IFEAT);
    unsigned short* __restrict__ xr = xg + (size_t)row * KD;

    #pragma unroll
    for (int i = 0; i < 4; ++i) {
        const float4 v = x4[i * 256 + t];
        float s = v.x + v.y + v.z + v.w;
        // one group = 32 lanes x 4 floats = 128 contiguous elems
        #pragma unroll
        for (int off = 1; off <= 16; off <<= 1) s += __shfl_xor(s, off);
        if ((t & 31) == 0) {
            const int g = i * 8 + (t >> 5);
            xr[64 + g] = f2bf(s);
        }
    }
    if (t < 64) xr[t] = f2bf(x[(size_t)row * IFEAT + t]);
}

// ---------------- GEMM: out[rows][OFEAT] = xg @ weff^T + bias via MFMA
// Block = 4 waves = 128x128 tile (2x2 waves, each wave 64x64 = 2x2 of 32x32).
// Both operand tiles staged to LDS once per block. Epilogue: per-wave
// double-buffered LDS transpose -> dwordx4 through-L2 stores; lgkm-only waits.
__global__ __launch_bounds__(256) void mfma_gemm_kernel(const unsigned short* __restrict__ xg,
                                                        const unsigned short* __restrict__ weff,
                                                        const float* __restrict__ bias,
                                                        float* __restrict__ out) {
    __shared__ unsigned short smem[2][128][KDP];   // [0]=xs, [1]=wsh; reused as epilogue scratch

    const int t    = threadIdx.x;
    const int wid  = t >> 6;
    const int lane = t & 63;
    const int r0 = blockIdx.y * 128;
    const int o0 = blockIdx.x * 128;

    // ---- stage: each operand tile is 128 rows x 96 shorts = 24KB contiguous.
    {
        const unsigned short* __restrict__ xsrc = xg   + (size_t)r0 * KD;
        const unsigned short* __restrict__ wsrc = weff + (size_t)o0 * KD;
        #pragma unroll
        for (int j = 0; j < 6; ++j) {
            const int i = j * 256 + t;           // 1536 16B chunks
            const int r = i / 12;
            const int c = i - r * 12;
            *(short8*)&smem[0][r][c * 8] = *(const short8*)(xsrc + i * 8);
            *(short8*)&smem[1][r][c * 8] = *(const short8*)(wsrc + i * 8);
        }
    }
    __syncthreads();

    const int rw = (wid >> 1) * 64;   // wave's row offset within tile
    const int ow = (wid & 1) * 64;    // wave's col offset within tile
    const int l31  = lane & 31;
    const int half = lane >> 5;       // 0 or 1
    const int koff = half * 8;

    f32x16 acc00 = {}, acc01 = {}, acc10 = {}, acc11 = {};
    #pragma unroll
    for (int ks = 0; ks < 6; ++ks) {
        const int k = koff + 16 * ks;
        const short8 a0 = *(const short8*)&smem[0][rw + l31][k];
        const short8 a1 = *(const short8*)&smem[0][rw + 32 + l31][k];
        const short8 b0 = *(const short8*)&smem[1][ow + l31][k];
        const short8 b1 = *(const short8*)&smem[1][ow + 32 + l31][k];
        acc00 = __builtin_amdgcn_mfma_f32_32x32x16_bf16(a0, b0, acc00, 0, 0, 0);
        acc01 = __builtin_amdgcn_mfma_f32_32x32x16_bf16(a0, b1, acc01, 0, 0, 0);
        acc10 = __builtin_amdgcn_mfma_f32_32x32x16_bf16(a1, b0, acc10, 0, 0, 0);
        acc11 = __builtin_amdgcn_mfma_f32_32x32x16_bf16(a1, b1, acc11, 0, 0, 0);
    }

    const int rb = r0 + rw;
    const int ob = o0 + ow;
    const float bb0 = bias[ob + l31];
    const float bb1 = bias[ob + 32 + l31];

    // ---- epilogue: all waves done reading tiles; reuse smem as scratch.
    __syncthreads();
    float* __restrict__ scratch = reinterpret_cast<float*>(&smem[0][0][0]);
    float* __restrict__ ltb = scratch + wid * 2304;   // 2 buffers x 1152 floats/wave

    #pragma unroll
    for (int ci = 0; ci < 4; ++ci) {
        float* __restrict__ lt = ltb + (ci & 1) * 1152;
        const f32x16& accA = (ci < 2) ? acc00 : acc10;   // cols ob..ob+31
        const f32x16& accB = (ci < 2) ? acc01 : acc11;   // cols ob+32..ob+63
        const int ibase = (ci & 1) * 8;
        // write 16 rows x 64 cols into scratch (bank-conflict-free)
        #pragma unroll
        for (int j = 0; j < 8; ++j) {
            const int row = (j & 3) + 8 * (j >> 2) + 4 * half;   // 0..15
            lt[row * LTP + l31]      = accA[ibase + j] + bb0;
            lt[row * LTP + 32 + l31] = accB[ibase + j] + bb1;
        }
        __builtin_amdgcn_sched_barrier(0);
        __builtin_amdgcn_s_waitcnt(0xc07f);   // lgkmcnt(0) only: ds_writes visible
        __builtin_amdgcn_sched_barrier(0);
        // read back row-major; one dwordx4 store per sub (1KB/instr wave-wide)
        const int cq = (lane & 15) * 4;
        #pragma unroll
        for (int sub = 0; sub < 4; ++sub) {
            const int row_l = sub * 4 + (lane >> 4);             // 0..15
            const f32x4 v = *(const f32x4*)&lt[row_l * LTP + cq];
            f32x4* __restrict__ dst =
                (f32x4*)(out + (size_t)(rb + ci * 16 + row_l) * OFEAT + ob + cq);
            *dst = v;   // regular through-L2 store: dirty-evict is a HW stream
        }
        // no vmcnt wait: double buffer covers the LDS reuse hazard (lgkm only)
    }
}

extern "C" void kernel_launch(void* const* d_in, const int* in_sizes, int n_in,
                              void* d_out, int out_size, void* d_ws, size_t ws_size,
                              hipStream_t stream) {
    const float* x       = (const float*)d_in[0];
    const int*   qweight = (const int*)d_in[1];
    const float* qscale  = (const float*)d_in[2];
    const int*   qzero   = (const int*)d_in[3];
    const float* bias    = (const float*)d_in[4];
    float*       out     = (float*)d_out;

    const int rows = in_sizes[0] / IFEAT;  // B*S = 8192

    unsigned short* xg   = (unsigned short*)d_ws;              // rows*96 bf16
    unsigned short* weff = xg + (size_t)rows * KD;             // O*96 bf16

    prep_kernel<<<rows + WBLKS, 256, 0, stream>>>(x, qweight, qscale, qzero, xg, weff);

    dim3 grid(OFEAT / 128, rows / 128);
    mfma_gemm_kernel<<<grid, 256, 0, stream>>>(xg, weff, bias, out);
}

// Round 15
// 51.451 us; speedup vs baseline: 1.0520x; 1.0520x over previous
//
#include <hip/hip_runtime.h>

// EXL2Linear — faithful to the reference's (quirky) unpack indexing:
// only W[:, 0:64] receives quantized codes; W[:, 64:] == qzero broadcast.
// out[r,o] = s0(o) * sum_{j<64} x[r,j]*uq(o,j) + sum_g qzero[o,g]*gsum[r,g] + bias[o]
// Collapsed to a K=96 bf16 MFMA GEMM: xg[rows][96] @ weff[O][96]^T.
// Round-12 epilogue (LDS transpose + NT dwordx4, lgkm-only waits) at HIGH
// OCCUPANCY: xg-only LDS staging (25.6KB), weff frags direct from L2,
// epilogue scratch reuses xs (single buffer; per-wave LDS is in-order so
// WAR needs no wait), launch_bounds(256,4) -> 4-5 blocks/CU.

constexpr int IFEAT  = 4096;
constexpr int OFEAT  = 4096;
constexpr int GROUPS = 32;   // IFEAT / 128
constexpr int KD     = 96;   // 64 quantized cols + 32 group sums
constexpr int KDP    = 100;  // padded LDS row (shorts): 2-way bank aliasing (free)
constexpr int WBLKS  = OFEAT / 256;  // 16 weff-prep blocks
constexpr int LTP    = 68;   // epilogue scratch row pitch (floats)

using short8 = __attribute__((ext_vector_type(8))) short;
using f32x4  = __attribute__((ext_vector_type(4))) float;
using f32x16 = __attribute__((ext_vector_type(16))) float;

static __device__ __forceinline__ unsigned short f2bf(float f) {
    union { float f; unsigned int u; } v; v.f = f;
    unsigned int lsb = (v.u >> 16) & 1;
    v.u += 0x7fff + lsb;           // round-to-nearest-even
    return (unsigned short)(v.u >> 16);
}

// ---------------- Fused prep: blocks [0,WBLKS) build weff[O][96];
// blocks [WBLKS, WBLKS+rows) build xg[row][96]. 8208 blocks = full TLP,
// read-bound at ~6.4 TB/s.
__global__ __launch_bounds__(256) void prep_kernel(const float* __restrict__ x,
                                                   const int* __restrict__ qweight,
                                                   const float* __restrict__ qscale,
                                                   const int* __restrict__ qzero,
                                                   unsigned short* __restrict__ xg,
                                                   unsigned short* __restrict__ weff) {
    const int t = threadIdx.x;
    if (blockIdx.x < WBLKS) {
        // ---- weff rows (dispatched first; tiny)
        const int o = blockIdx.x * 256 + t;
        const float s0 = qscale[(size_t)o * GROUPS];  // group-0 scale
        const unsigned int* qw = (const unsigned int*)qweight + (size_t)o * (IFEAT / 8);
        unsigned int q[8];
        #pragma unroll
        for (int c = 0; c < 8; ++c) q[c] = qw[c];
        unsigned short* wr = weff + (size_t)o * KD;
        #pragma unroll
        for (int j = 0; j < 64; ++j) {
            const int c = j & 7;
            const int i = j >> 3;
            const float uq = (float)((q[c] >> (i * 4)) & 15u);
            wr[j] = f2bf(uq * s0);
        }
        #pragma unroll
        for (int g = 0; g < GROUPS; ++g) {
            wr[64 + g] = f2bf((float)qzero[(size_t)o * GROUPS + g]);
        }
        return;
    }
    // ---- xg row
    const int row = blockIdx.x - WBLKS;
    const float4* __restrict__ x4 = (const float4*)(x + (size_t)row * IFEAT);
    unsigned short* __restrict__ xr = xg + (size_t)row * KD;

    #pragma unroll
    for (int i = 0; i < 4; ++i) {
        const float4 v = x4[i * 256 + t];
        float s = v.x + v.y + v.z + v.w;
        // one group = 32 lanes x 4 floats = 128 contiguous elems
        #pragma unroll
        for (int off = 1; off <= 16; off <<= 1) s += __shfl_xor(s, off);
        if ((t & 31) == 0) {
            const int g = i * 8 + (t >> 5);
            xr[64 + g] = f2bf(s);
        }
    }
    if (t < 64) xr[t] = f2bf(x[(size_t)row * IFEAT + t]);
}

// ---------------- GEMM: out[rows][OFEAT] = xg @ weff^T + bias via MFMA
// Block = 4 waves = 128x128 tile (2x2 waves, each wave 64x64 = 2x2 of 32x32).
// xg tile in LDS (25.6KB); weff fragments direct from L2. Epilogue: LDS
// transpose (scratch reuses xs) -> dwordx4 NT stores; lgkm-only waits.
__global__ __launch_bounds__(256, 4) void mfma_gemm_kernel(const unsigned short* __restrict__ xg,
                                                           const unsigned short* __restrict__ weff,
                                                           const float* __restrict__ bias,
                                                           float* __restrict__ out) {
    __shared__ unsigned short xs[128][KDP];   // xg tile; reused as epilogue scratch

    const int t    = threadIdx.x;
    const int wid  = t >> 6;
    const int lane = t & 63;
    const int r0 = blockIdx.y * 128;
    const int o0 = blockIdx.x * 128;

    // ---- stage xg tile: 128 rows x 96 shorts = 24KB contiguous.
    {
        const unsigned short* __restrict__ xsrc = xg + (size_t)r0 * KD;
        #pragma unroll
        for (int j = 0; j < 6; ++j) {
            const int i = j * 256 + t;           // 1536 16B chunks
            const int r = i / 12;
            const int c = i - r * 12;
            *(short8*)&xs[r][c * 8] = *(const short8*)(xsrc + i * 8);
        }
    }
    __syncthreads();

    const int rw = (wid >> 1) * 64;   // wave's row offset within tile
    const int ow = (wid & 1) * 64;    // wave's col offset within tile
    const int l31  = lane & 31;
    const int half = lane >> 5;       // 0 or 1
    const int koff = half * 8;

    const short8* __restrict__ bp0 = (const short8*)(weff + (size_t)(o0 + ow + l31) * KD + koff);
    const short8* __restrict__ bp1 = (const short8*)(weff + (size_t)(o0 + ow + 32 + l31) * KD + koff);

    f32x16 acc00 = {}, acc01 = {}, acc10 = {}, acc11 = {};
    #pragma unroll
    for (int ks = 0; ks < 6; ++ks) {
        const int k = koff + 16 * ks;
        const short8 a0 = *(const short8*)&xs[rw + l31][k];
        const short8 a1 = *(const short8*)&xs[rw + 32 + l31][k];
        const short8 b0 = bp0[ks * 2];   // advance 16 shorts per K-step
        const short8 b1 = bp1[ks * 2];
        acc00 = __builtin_amdgcn_mfma_f32_32x32x16_bf16(a0, b0, acc00, 0, 0, 0);
        acc01 = __builtin_amdgcn_mfma_f32_32x32x16_bf16(a0, b1, acc01, 0, 0, 0);
        acc10 = __builtin_amdgcn_mfma_f32_32x32x16_bf16(a1, b0, acc10, 0, 0, 0);
        acc11 = __builtin_amdgcn_mfma_f32_32x32x16_bf16(a1, b1, acc11, 0, 0, 0);
    }

    const int rb = r0 + rw;
    const int ob = o0 + ow;
    const float bb0 = bias[ob + l31];
    const float bb1 = bias[ob + 32 + l31];

    // ---- epilogue: all waves done reading xs; reuse it as float scratch.
    __syncthreads();
    float* __restrict__ scratch = reinterpret_cast<float*>(&xs[0][0]);
    float* __restrict__ lt = scratch + wid * 1152;   // 1152 floats/wave (single buffer)

    #pragma unroll
    for (int ci = 0; ci < 4; ++ci) {
        const f32x16& accA = (ci < 2) ? acc00 : acc10;   // cols ob..ob+31
        const f32x16& accB = (ci < 2) ? acc01 : acc11;   // cols ob+32..ob+63
        const int ibase = (ci & 1) * 8;
        // write 16 rows x 64 cols into scratch (bank-conflict-free).
        // WAR vs previous ci's reads is safe: per-wave LDS ops are in-order.
        #pragma unroll
        for (int j = 0; j < 8; ++j) {
            const int row = (j & 3) + 8 * (j >> 2) + 4 * half;   // 0..15
            lt[row * LTP + l31]      = accA[ibase + j] + bb0;
            lt[row * LTP + 32 + l31] = accB[ibase + j] + bb1;
        }
        __builtin_amdgcn_sched_barrier(0);
        __builtin_amdgcn_s_waitcnt(0xc07f);   // lgkmcnt(0) only: ds_writes visible
        __builtin_amdgcn_sched_barrier(0);
        // read back row-major; one dwordx4 NT store per sub (1KB/instr wave-wide)
        const int cq = (lane & 15) * 4;
        #pragma unroll
        for (int sub = 0; sub < 4; ++sub) {
            const int row_l = sub * 4 + (lane >> 4);             // 0..15
            const f32x4 v = *(const f32x4*)&lt[row_l * LTP + cq];
            f32x4* __restrict__ dst =
                (f32x4*)(out + (size_t)(rb + ci * 16 + row_l) * OFEAT + ob + cq);
            __builtin_nontemporal_store(v, dst);
        }
    }
}

extern "C" void kernel_launch(void* const* d_in, const int* in_sizes, int n_in,
                              void* d_out, int out_size, void* d_ws, size_t ws_size,
                              hipStream_t stream) {
    const float* x       = (const float*)d_in[0];
    const int*   qweight = (const int*)d_in[1];
    const float* qscale  = (const float*)d_in[2];
    const int*   qzero   = (const int*)d_in[3];
    const float* bias    = (const float*)d_in[4];
    float*       out     = (float*)d_out;

    const int rows = in_sizes[0] / IFEAT;  // B*S = 8192

    unsigned short* xg   = (unsigned short*)d_ws;              // rows*96 bf16
    unsigned short* weff = xg + (size_t)rows * KD;             // O*96 bf16

    prep_kernel<<<rows + WBLKS, 256, 0, stream>>>(x, qweight, qscale, qzero, xg, weff);

    dim3 grid(OFEAT / 128, rows / 128);
    mfma_gemm_kernel<<<grid, 256, 0, stream>>>(xg, weff, bias, out);
}

// Round 16
// 51.379 us; speedup vs baseline: 1.0535x; 1.0014x over previous
//
#include <hip/hip_runtime.h>

// EXL2Linear — faithful to the reference's (quirky) unpack indexing:
// only W[:, 0:64] receives quantized codes; W[:, 64:] == qzero broadcast.
// out[r,o] = s0(o) * sum_{j<64} x[r,j]*uq(o,j) + sum_g qzero[o,g]*gsum[r,g] + bias[o]
// Collapsed to a K=96 bf16 MFMA GEMM: xg[rows][96] @ weff[O][96]^T.
// Round-15 (xg-only LDS staging, transposed NT epilogue, launch_bounds(256,4))
// + T1 XCD-AWARE CHUNKED SWIZZLE: each XCD owns 256 contiguous tiles
// (8 row-panels) -> L2 containment for xg slice + contiguous write region.

constexpr int IFEAT  = 4096;
constexpr int OFEAT  = 4096;
constexpr int GROUPS = 32;   // IFEAT / 128
constexpr int KD     = 96;   // 64 quantized cols + 32 group sums
constexpr int KDP    = 100;  // padded LDS row (shorts): 2-way bank aliasing (free)
constexpr int WBLKS  = OFEAT / 256;  // 16 weff-prep blocks
constexpr int LTP    = 68;   // epilogue scratch row pitch (floats)
constexpr int NXCD   = 8;

using short8 = __attribute__((ext_vector_type(8))) short;
using f32x4  = __attribute__((ext_vector_type(4))) float;
using f32x16 = __attribute__((ext_vector_type(16))) float;

static __device__ __forceinline__ unsigned short f2bf(float f) {
    union { float f; unsigned int u; } v; v.f = f;
    unsigned int lsb = (v.u >> 16) & 1;
    v.u += 0x7fff + lsb;           // round-to-nearest-even
    return (unsigned short)(v.u >> 16);
}

// ---------------- Fused prep: blocks [0,WBLKS) build weff[O][96];
// blocks [WBLKS, WBLKS+rows) build xg[row][96]. 8208 blocks = full TLP,
// read-bound at ~6.4 TB/s.
__global__ __launch_bounds__(256) void prep_kernel(const float* __restrict__ x,
                                                   const int* __restrict__ qweight,
                                                   const float* __restrict__ qscale,
                                                   const int* __restrict__ qzero,
                                                   unsigned short* __restrict__ xg,
                                                   unsigned short* __restrict__ weff) {
    const int t = threadIdx.x;
    if (blockIdx.x < WBLKS) {
        // ---- weff rows (dispatched first; tiny)
        const int o = blockIdx.x * 256 + t;
        const float s0 = qscale[(size_t)o * GROUPS];  // group-0 scale
        const unsigned int* qw = (const unsigned int*)qweight + (size_t)o * (IFEAT / 8);
        unsigned int q[8];
        #pragma unroll
        for (int c = 0; c < 8; ++c) q[c] = qw[c];
        unsigned short* wr = weff + (size_t)o * KD;
        #pragma unroll
        for (int j = 0; j < 64; ++j) {
            const int c = j & 7;
            const int i = j >> 3;
            const float uq = (float)((q[c] >> (i * 4)) & 15u);
            wr[j] = f2bf(uq * s0);
        }
        #pragma unroll
        for (int g = 0; g < GROUPS; ++g) {
            wr[64 + g] = f2bf((float)qzero[(size_t)o * GROUPS + g]);
        }
        return;
    }
    // ---- xg row
    const int row = blockIdx.x - WBLKS;
    const float4* __restrict__ x4 = (const float4*)(x + (size_t)row * IFEAT);
    unsigned short* __restrict__ xr = xg + (size_t)row * KD;

    #pragma unroll
    for (int i = 0; i < 4; ++i) {
        const float4 v = x4[i * 256 + t];
        float s = v.x + v.y + v.z + v.w;
        // one group = 32 lanes x 4 floats = 128 contiguous elems
        #pragma unroll
        for (int off = 1; off <= 16; off <<= 1) s += __shfl_xor(s, off);
        if ((t & 31) == 0) {
            const int g = i * 8 + (t >> 5);
            xr[64 + g] = f2bf(s);
        }
    }
    if (t < 64) xr[t] = f2bf(x[(size_t)row * IFEAT + t]);
}

// ---------------- GEMM: out[rows][OFEAT] = xg @ weff^T + bias via MFMA
// Block = 4 waves = 128x128 tile (2x2 waves, each wave 64x64 = 2x2 of 32x32).
// xg tile in LDS (25.6KB); weff fragments direct from L2. Epilogue: LDS
// transpose (scratch reuses xs) -> dwordx4 NT stores; lgkm-only waits.
// 1D grid with XCD-chunked tile assignment (ntiles % 8 == 0, bijective).
__global__ __launch_bounds__(256, 4) void mfma_gemm_kernel(const unsigned short* __restrict__ xg,
                                                           const unsigned short* __restrict__ weff,
                                                           const float* __restrict__ bias,
                                                           float* __restrict__ out,
                                                           int ntiles) {
    __shared__ unsigned short xs[128][KDP];   // xg tile; reused as epilogue scratch

    const int t    = threadIdx.x;
    const int wid  = t >> 6;
    const int lane = t & 63;

    // T1 chunked swizzle: XCD k owns tiles [k*cpx, (k+1)*cpx)
    const int cpx  = ntiles / NXCD;
    const int tile = (blockIdx.x % NXCD) * cpx + blockIdx.x / NXCD;
    const int r0 = (tile >> 5) * 128;       // 32 o-tiles per row-panel
    const int o0 = (tile & 31) * 128;

    // ---- stage xg tile: 128 rows x 96 shorts = 24KB contiguous.
    {
        const unsigned short* __restrict__ xsrc = xg + (size_t)r0 * KD;
        #pragma unroll
        for (int j = 0; j < 6; ++j) {
            const int i = j * 256 + t;           // 1536 16B chunks
            const int r = i / 12;
            const int c = i - r * 12;
            *(short8*)&xs[r][c * 8] = *(const short8*)(xsrc + i * 8);
        }
    }
    __syncthreads();

    const int rw = (wid >> 1) * 64;   // wave's row offset within tile
    const int ow = (wid & 1) * 64;    // wave's col offset within tile
    const int l31  = lane & 31;
    const int half = lane >> 5;       // 0 or 1
    const int koff = half * 8;

    const short8* __restrict__ bp0 = (const short8*)(weff + (size_t)(o0 + ow + l31) * KD + koff);
    const short8* __restrict__ bp1 = (const short8*)(weff + (size_t)(o0 + ow + 32 + l31) * KD + koff);

    f32x16 acc00 = {}, acc01 = {}, acc10 = {}, acc11 = {};
    #pragma unroll
    for (int ks = 0; ks < 6; ++ks) {
        const int k = koff + 16 * ks;
        const short8 a0 = *(const short8*)&xs[rw + l31][k];
        const short8 a1 = *(const short8*)&xs[rw + 32 + l31][k];
        const short8 b0 = bp0[ks * 2];   // advance 16 shorts per K-step
        const short8 b1 = bp1[ks * 2];
        acc00 = __builtin_amdgcn_mfma_f32_32x32x16_bf16(a0, b0, acc00, 0, 0, 0);
        acc01 = __builtin_amdgcn_mfma_f32_32x32x16_bf16(a0, b1, acc01, 0, 0, 0);
        acc10 = __builtin_amdgcn_mfma_f32_32x32x16_bf16(a1, b0, acc10, 0, 0, 0);
        acc11 = __builtin_amdgcn_mfma_f32_32x32x16_bf16(a1, b1, acc11, 0, 0, 0);
    }

    const int rb = r0 + rw;
    const int ob = o0 + ow;
    const float bb0 = bias[ob + l31];
    const float bb1 = bias[ob + 32 + l31];

    // ---- epilogue: all waves done reading xs; reuse it as float scratch.
    __syncthreads();
    float* __restrict__ scratch = reinterpret_cast<float*>(&xs[0][0]);
    float* __restrict__ lt = scratch + wid * 1152;   // 1152 floats/wave (single buffer)

    #pragma unroll
    for (int ci = 0; ci < 4; ++ci) {
        const f32x16& accA = (ci < 2) ? acc00 : acc10;   // cols ob..ob+31
        const f32x16& accB = (ci < 2) ? acc01 : acc11;   // cols ob+32..ob+63
        const int ibase = (ci & 1) * 8;
        // write 16 rows x 64 cols into scratch (bank-conflict-free).
        // WAR vs previous ci's reads is safe: per-wave LDS ops are in-order.
        #pragma unroll
        for (int j = 0; j < 8; ++j) {
            const int row = (j & 3) + 8 * (j >> 2) + 4 * half;   // 0..15
            lt[row * LTP + l31]      = accA[ibase + j] + bb0;
            lt[row * LTP + 32 + l31] = accB[ibase + j] + bb1;
        }
        __builtin_amdgcn_sched_barrier(0);
        __builtin_amdgcn_s_waitcnt(0xc07f);   // lgkmcnt(0) only: ds_writes visible
        __builtin_amdgcn_sched_barrier(0);
        // read back row-major; one dwordx4 NT store per sub (1KB/instr wave-wide)
        const int cq = (lane & 15) * 4;
        #pragma unroll
        for (int sub = 0; sub < 4; ++sub) {
            const int row_l = sub * 4 + (lane >> 4);             // 0..15
            const f32x4 v = *(const f32x4*)&lt[row_l * LTP + cq];
            f32x4* __restrict__ dst =
                (f32x4*)(out + (size_t)(rb + ci * 16 + row_l) * OFEAT + ob + cq);
            __builtin_nontemporal_store(v, dst);
        }
    }
}

extern "C" void kernel_launch(void* const* d_in, const int* in_sizes, int n_in,
                              void* d_out, int out_size, void* d_ws, size_t ws_size,
                              hipStream_t stream) {
    const float* x       = (const float*)d_in[0];
    const int*   qweight = (const int*)d_in[1];
    const float* qscale  = (const float*)d_in[2];
    const int*   qzero   = (const int*)d_in[3];
    const float* bias    = (const float*)d_in[4];
    float*       out     = (float*)d_out;

    const int rows = in_sizes[0] / IFEAT;  // B*S = 8192

    unsigned short* xg   = (unsigned short*)d_ws;              // rows*96 bf16
    unsigned short* weff = xg + (size_t)rows * KD;             // O*96 bf16

    prep_kernel<<<rows + WBLKS, 256, 0, stream>>>(x, qweight, qscale, qzero, xg, weff);

    const int ntiles = (OFEAT / 128) * (rows / 128);   // 2048, % 8 == 0
    mfma_gemm_kernel<<<ntiles, 256, 0, stream>>>(xg, weff, bias, out, ntiles);
}